// Round 20
// baseline (526.898 us; speedup 1.0000x reference)
//
#include <hip/hip_runtime.h>
#include <hip/hip_bf16.h>

#define EMBED_DIM 4096
#define PROJ_DIM  1024
#define NROWS     8192
#define NPART     8
#define PARTSZ    128
#define MAXTILES  128
#define KSPLIT    8
#define KCHUNK    512    // EMBED_DIM / KSPLIT
#define KSEL      256    // gathered columns per row
#define BK        32     // 64B LDS rows (gemm2)

typedef __bf16 bf16x8_t __attribute__((ext_vector_type(8)));
typedef float  f32x4_t  __attribute__((ext_vector_type(4)));
typedef unsigned short ushort8_t __attribute__((ext_vector_type(8)));

__device__ __forceinline__ unsigned short f2bf(float f) {
  unsigned u = __builtin_bit_cast(unsigned, f);
  u += 0x7fffu + ((u >> 16) & 1u);   // round-to-nearest-even
  return (unsigned short)(u >> 16);
}

__device__ __forceinline__ float bf2f(unsigned short u) {
  unsigned x = (unsigned)u << 16;
  return __builtin_bit_cast(float, x);
}

__device__ __forceinline__ void stage16(const void* g, void* l) {
  __builtin_amdgcn_global_load_lds(
      (const __attribute__((address_space(1))) unsigned int*)g,
      (__attribute__((address_space(3))) unsigned int*)l, 16, 0, 0);
}

// ---- Wb = bf16(W) [4096,1024]; WTb = bf16(W^T) [1024,4096] ----
__global__ __launch_bounds__(256) void prep_w(const float* __restrict__ W,
                                              unsigned short* __restrict__ Wb,
                                              unsigned short* __restrict__ WTb) {
  __shared__ float t[32][33];
  const int px = threadIdx.x & 31;
  const int ty = threadIdx.x >> 5;
  const int p0 = blockIdx.x * 32;
  const int d0 = blockIdx.y * 32;
#pragma unroll
  for (int i = 0; i < 32; i += 8) {
    float v = W[(size_t)(d0 + ty + i) * PROJ_DIM + p0 + px];
    t[ty + i][px] = v;
    Wb[(size_t)(d0 + ty + i) * PROJ_DIM + p0 + px] = f2bf(v);
  }
  __syncthreads();
#pragma unroll
  for (int i = 0; i < 32; i += 8) {
    WTb[(size_t)(p0 + ty + i) * EMBED_DIM + d0 + px] = f2bf(t[px][ty + i]);
  }
}

// ---- single-block bucketing: hist -> scan -> tile table -> scatter ----
__global__ __launch_bounds__(1024) void k_bucket(const int* __restrict__ subs,
                                                 int* __restrict__ tiles,
                                                 int* __restrict__ n_tiles,
                                                 int* __restrict__ perm) {
  __shared__ int h[64], off[64], cur[64];
  const int t = threadIdx.x;
  if (t < 64) h[t] = 0;
  __syncthreads();
  for (int r = t; r < NROWS; r += 1024)
    atomicAdd(&h[subs[2 * r] * NPART + subs[2 * r + 1]], 1);
  __syncthreads();
  if (t < 64) {  // threads 0..63 == wave 0
    int v = h[t], incl = v;
#pragma unroll
    for (int o = 1; o < 64; o <<= 1) { int n = __shfl_up(incl, o); if (t >= o) incl += n; }
    int excl = incl - v;
    off[t] = excl; cur[t] = 0;
    int tc = (v + 127) >> 7, tincl = tc;
#pragma unroll
    for (int o = 1; o < 64; o <<= 1) { int n = __shfl_up(tincl, o); if (t >= o) tincl += n; }
    int texcl = tincl - tc;
    for (int k = 0; k < tc; ++k) {
      tiles[3 * (texcl + k) + 0] = excl + k * 128;
      tiles[3 * (texcl + k) + 1] = min(128, v - k * 128);
      tiles[3 * (texcl + k) + 2] = t;
    }
    if (t == 63) *n_tiles = tincl;
  }
  __syncthreads();
  for (int r = t; r < NROWS; r += 1024) {
    int p = subs[2 * r] * NPART + subs[2 * r + 1];
    perm[off[p] + atomicAdd(&cur[p], 1)] = r;
  }
}

// ---- GEMM1 fused, BARRIER-FREE, LDS-FREE dataflow:
// every MFMA fragment is loaded per-lane straight from global memory;
// delta = bf16(source-base) computed in VALU per fragment. No __syncthreads
// -> the compiler emits COUNTED vmcnt waits and pipelines loads freely.
// 512 thr, 8 waves (2m x 4n), tile 128 rows x 256 cols, XCD-pinned z=bid&7.
// Ypart[z][i, 0:256] = bf16( delta[perm[i], z*512..] @ Wsel ) ----
__global__ __launch_bounds__(512, 4) void gemm1(
    const float* __restrict__ base, const float* __restrict__ source,
    const unsigned short* __restrict__ WTb,    // [1024,4096] bf16
    const int* __restrict__ perm,
    const int* __restrict__ tiles, const int* __restrict__ n_tiles,
    unsigned short* __restrict__ Ypart) {      // [KSPLIT][8192][256] bf16
  const int bid  = blockIdx.x;         // [0,1024)
  const int z    = bid & 7;            // XCD-pinned K chunk
  const int tile = bid >> 3;           // [0,128)
  if (tile >= *n_tiles) return;
  const int start = tiles[3 * tile + 0];
  const int cnt   = tiles[3 * tile + 1];
  const int bkt   = tiles[3 * tile + 2];
  const int s0    = bkt >> 3, s1 = bkt & 7;
  const int kbase = z * KCHUNK;

  const int lane = threadIdx.x & 63;
  const int wave = threadIdx.x >> 6;   // 0..7
  const int wm   = wave >> 2;          // 0..1
  const int wn   = wave & 3;           // 0..3
  const int l15  = lane & 15;
  const int lk   = (lane >> 4) * 8;    // k sub-offset within 32-chunk

  // A row pointers: 4 frags, rows wm*64 + i*16 + l15 (gathered via perm)
  const float* ab[4];
  const float* asx[4];
  int rowl[4];
#pragma unroll
  for (int i = 0; i < 4; ++i) {
    rowl[i] = wm * 64 + i * 16 + l15;
    const int g = perm[start + min(rowl[i], cnt - 1)];
    ab[i]  = base   + (size_t)g * EMBED_DIM + kbase + lk;
    asx[i] = source + (size_t)g * EMBED_DIM + kbase + lk;
  }
  // B row pointers: 4 frags, selected W-cols wn*64 + j*16 + l15
  const unsigned short* bp[4];
#pragma unroll
  for (int j = 0; j < 4; ++j) {
    const int brow = wn * 64 + j * 16 + l15;
    const int sel  = (brow < 128) ? (s0 * PARTSZ + brow)
                                  : (s1 * PARTSZ + brow - 128);
    bp[j] = WTb + (size_t)sel * EMBED_DIM + kbase + lk;
  }

  f32x4_t acc[4][4] = {};

#pragma unroll 2
  for (int kt = 0; kt < KCHUNK; kt += 32) {
    bf16x8_t bv[4], af[4];
#pragma unroll
    for (int j = 0; j < 4; ++j)
      bv[j] = *reinterpret_cast<const bf16x8_t*>(bp[j] + kt);
#pragma unroll
    for (int i = 0; i < 4; ++i) {
      f32x4_t b0 = *reinterpret_cast<const f32x4_t*>(ab[i] + kt);
      f32x4_t b1 = *reinterpret_cast<const f32x4_t*>(ab[i] + kt + 4);
      f32x4_t t0 = *reinterpret_cast<const f32x4_t*>(asx[i] + kt);
      f32x4_t t1 = *reinterpret_cast<const f32x4_t*>(asx[i] + kt + 4);
      bf16x8_t a;
      a[0] = (__bf16)(t0[0] - b0[0]); a[1] = (__bf16)(t0[1] - b0[1]);
      a[2] = (__bf16)(t0[2] - b0[2]); a[3] = (__bf16)(t0[3] - b0[3]);
      a[4] = (__bf16)(t1[0] - b1[0]); a[5] = (__bf16)(t1[1] - b1[1]);
      a[6] = (__bf16)(t1[2] - b1[2]); a[7] = (__bf16)(t1[3] - b1[3]);
      af[i] = a;
    }
    // swapped operands -> lane holds 4 consecutive output cols of one row
#pragma unroll
    for (int i = 0; i < 4; ++i)
#pragma unroll
      for (int j = 0; j < 4; ++j)
        acc[i][j] = __builtin_amdgcn_mfma_f32_16x16x32_bf16(bv[j], af[i],
                                                            acc[i][j], 0, 0, 0);
  }

  unsigned short* Yo = Ypart + (size_t)z * NROWS * KSEL;
#pragma unroll
  for (int i = 0; i < 4; ++i) {
    if (rowl[i] < cnt) {
#pragma unroll
      for (int j = 0; j < 4; ++j) {
        const int col = wn * 64 + j * 16 + (lane >> 4) * 4;
        ushort4 o;
        o.x = f2bf(acc[i][j][0]); o.y = f2bf(acc[i][j][1]);
        o.z = f2bf(acc[i][j][2]); o.w = f2bf(acc[i][j][3]);
        *reinterpret_cast<ushort4*>(
            &Yo[(size_t)(start + rowl[i]) * KSEL + col]) = o;
      }
    }
  }
}

// ---- combine bf16 split-K partials (8) -> Ysel bf16 [8192, 256] ----
__global__ __launch_bounds__(256) void combine(const unsigned short* __restrict__ Yp,
                                               unsigned short* __restrict__ Ysel) {
  const int total = NROWS * KSEL / 4;
  const int stride4 = NROWS * KSEL / 4;   // in ushort4 units
  for (int i = blockIdx.x * blockDim.x + threadIdx.x; i < total;
       i += gridDim.x * blockDim.x) {
    float sx = 0.f, sy = 0.f, sz = 0.f, sw = 0.f;
#pragma unroll
    for (int z = 0; z < KSPLIT; ++z) {
      ushort4 v = ((const ushort4*)Yp)[(size_t)z * stride4 + i];
      sx += bf2f(v.x); sy += bf2f(v.y); sz += bf2f(v.z); sw += bf2f(v.w);
    }
    ushort4 o;
    o.x = f2bf(sx); o.y = f2bf(sy); o.z = f2bf(sz); o.w = f2bf(sw);
    ((ushort4*)Ysel)[i] = o;
  }
}

// ---- GEMM2: 512 threads, tile 128 rows x 256 cols, BK=32, 2-phase dbuf,
// XCD-pinned (round-15 proven, byte-identical).
// out[perm[i],:] = base[perm[i],:] + Ysel[i,:] @ Wsel^T ----
__global__ __launch_bounds__(512) void gemm2(
    const unsigned short* __restrict__ Ysel,   // [8192, 256] bf16
    const unsigned short* __restrict__ Wb,     // [4096,1024] bf16
    const int* __restrict__ perm,
    const int* __restrict__ tiles, const int* __restrict__ n_tiles,
    const float* __restrict__ base, float* __restrict__ out) {
  __shared__ __attribute__((aligned(16))) __bf16 As[2][128 * BK];  // 8KB/buf
  __shared__ __attribute__((aligned(16))) __bf16 Bs[2][256 * BK];  // 16KB/buf

  const int bid  = blockIdx.x + blockIdx.y * gridDim.x;
  const int xcd  = bid & 7;
  const int j_   = bid >> 3;           // [0,256)
  const int tile = j_ & 127;
  const int npnl = xcd * 2 + (j_ >> 7);  // [0,16)

  if (tile >= *n_tiles) return;
  const int start = tiles[3 * tile + 0];
  const int cnt   = tiles[3 * tile + 1];
  const int bkt   = tiles[3 * tile + 2];
  const int s0    = bkt >> 3, s1 = bkt & 7;
  const int n0    = npnl * 256;

  const int tid  = threadIdx.x;        // 0..511
  const int lane = tid & 63;
  const int wave = tid >> 6;           // 0..7
  const int wm   = wave >> 2;          // 0..1
  const int wn   = wave & 3;           // 0..3

  const int arow = tid >> 2;           // 0..127
  const int akel = (tid & 3) * 8;
  const int arc  = arow < cnt ? arow : 0;
  const unsigned short* aptr = Ysel + (size_t)(start + arc) * KSEL + akel;

  const unsigned short* bptr[2];
#pragma unroll
  for (int q = 0; q < 2; ++q) {
    const int sidx = q * 512 + tid;
    const int brow = sidx >> 2;        // 0..255
    bptr[q] = Wb + (size_t)(n0 + brow) * PROJ_DIM + (sidx & 3) * 8;
  }

#define STAGE2(buf, kt)                                                        \
  {                                                                            \
    const int sp   = ((kt) < 128) ? s0 : s1;                                   \
    const int coff = sp * PARTSZ + ((kt) & 127);                               \
    stage16(aptr + (kt), (char*)&As[buf][0] + tid * 16);                       \
    stage16(bptr[0] + coff, (char*)&Bs[buf][0] + tid * 16);                    \
    stage16(bptr[1] + coff, (char*)&Bs[buf][0] + 8192 + tid * 16);             \
  }

  f32x4_t acc[4][4] = {};

  STAGE2(0, 0);
  __syncthreads();
  int cur = 0;
#pragma unroll
  for (int kt = 0; kt < KSEL; kt += BK) {
    if (kt + BK < KSEL) STAGE2(cur ^ 1, kt + BK);
    bf16x8_t af[4], bv[4];
#pragma unroll
    for (int i = 0; i < 4; ++i)
      af[i] = *reinterpret_cast<const bf16x8_t*>(
          &As[cur][(wm * 64 + i * 16 + (lane & 15)) * BK + (lane >> 4) * 8]);
#pragma unroll
    for (int j = 0; j < 4; ++j)
      bv[j] = *reinterpret_cast<const bf16x8_t*>(
          &Bs[cur][(wn * 64 + j * 16 + (lane & 15)) * BK + (lane >> 4) * 8]);
    // swapped operands -> lane holds 4 consecutive output cols of one row
#pragma unroll
    for (int i = 0; i < 4; ++i)
#pragma unroll
      for (int j = 0; j < 4; ++j)
        acc[i][j] = __builtin_amdgcn_mfma_f32_16x16x32_bf16(bv[j], af[i],
                                                            acc[i][j], 0, 0, 0);
    __syncthreads();
    cur ^= 1;
  }

#pragma unroll
  for (int i = 0; i < 4; ++i) {
    const int row_local = wm * 64 + i * 16 + (lane & 15);
    if (row_local < cnt) {
      const int grow = perm[start + row_local];
#pragma unroll
      for (int j = 0; j < 4; ++j) {
        const int col = n0 + wn * 64 + j * 16 + (lane >> 4) * 4;
        const size_t o = (size_t)grow * EMBED_DIM + col;
        f32x4_t b4 = *reinterpret_cast<const f32x4_t*>(&base[o]);
        *reinterpret_cast<f32x4_t*>(&out[o]) = acc[i][j] + b4;
      }
    }
  }
}

extern "C" void kernel_launch(void* const* d_in, const int* in_sizes, int n_in,
                              void* d_out, int out_size, void* d_ws, size_t ws_size,
                              hipStream_t stream) {
  const float* base   = (const float*)d_in[0];
  const float* source = (const float*)d_in[1];
  const int*   subs   = (const int*)d_in[2];
  const float* W      = (const float*)d_in[3];
  float* out = (float*)d_out;

  // d_out scratch (dead before gemm2 writes out):
  //   Ypart bf16 [8][8192][256] @ 0   (32 MB; d_out is 128 MB)
  unsigned short* Ypart = (unsigned short*)d_out;

  // ws: Wb 8MB | WTb 8MB | Ysel 4MB | meta
  char* ws = (char*)d_ws;
  unsigned short* Wb   = (unsigned short*)(ws);
  unsigned short* WTb  = (unsigned short*)(ws + (8u << 20));
  unsigned short* Ysel = (unsigned short*)(ws + (16u << 20));
  char* meta = ws + (21u << 20);
  int* n_tiles = (int*)(meta);
  int* tiles   = (int*)(meta + 256);   // 128*3 ints
  int* perm    = (int*)(meta + 4096);  // 8192 ints

  k_bucket<<<1, 1024, 0, stream>>>(subs, tiles, n_tiles, perm);

  prep_w<<<dim3(PROJ_DIM / 32, EMBED_DIM / 32), 256, 0, stream>>>(W, Wb, WTb);

  gemm1<<<MAXTILES * KSPLIT, 512, 0, stream>>>(base, source, WTb, perm,
                                               tiles, n_tiles, Ypart);
  combine<<<1024, 256, 0, stream>>>(Ypart, Ysel);

  gemm2<<<dim3(MAXTILES, EMBED_DIM / 256), 512, 0, stream>>>(Ysel, Wb, perm, tiles,
                                                             n_tiles, base, out);
}

// Round 21
// 202.785 us; speedup vs baseline: 2.5983x; 2.5983x over previous
//
#include <hip/hip_runtime.h>
#include <hip/hip_bf16.h>

#define EMBED_DIM 4096
#define PROJ_DIM  1024
#define NROWS     8192
#define NPART     8
#define PARTSZ    128
#define MAXTILES  128
#define KSPLIT    8
#define KCHUNK    512    // EMBED_DIM / KSPLIT
#define KSEL      256    // gathered columns per row
#define BK        32     // 64B LDS rows: bank-spread ds_read_b128

typedef __bf16 bf16x8_t __attribute__((ext_vector_type(8)));
typedef float  f32x4_t  __attribute__((ext_vector_type(4)));
typedef unsigned short ushort8_t __attribute__((ext_vector_type(8)));

__device__ __forceinline__ unsigned short f2bf(float f) {
  unsigned u = __builtin_bit_cast(unsigned, f);
  u += 0x7fffu + ((u >> 16) & 1u);   // round-to-nearest-even
  return (unsigned short)(u >> 16);
}

__device__ __forceinline__ float bf2f(unsigned short u) {
  unsigned x = (unsigned)u << 16;
  return __builtin_bit_cast(float, x);
}

__device__ __forceinline__ void stage16(const void* g, void* l) {
  __builtin_amdgcn_global_load_lds(
      (const __attribute__((address_space(1))) unsigned int*)g,
      (__attribute__((address_space(3))) unsigned int*)l, 16, 0, 0);
}

// ---- Wb = bf16(W) [4096,1024]; WTb = bf16(W^T) [1024,4096] ----
__global__ __launch_bounds__(256) void prep_w(const float* __restrict__ W,
                                              unsigned short* __restrict__ Wb,
                                              unsigned short* __restrict__ WTb) {
  __shared__ float t[32][33];
  const int px = threadIdx.x & 31;
  const int ty = threadIdx.x >> 5;
  const int p0 = blockIdx.x * 32;
  const int d0 = blockIdx.y * 32;
#pragma unroll
  for (int i = 0; i < 32; i += 8) {
    float v = W[(size_t)(d0 + ty + i) * PROJ_DIM + p0 + px];
    t[ty + i][px] = v;
    Wb[(size_t)(d0 + ty + i) * PROJ_DIM + p0 + px] = f2bf(v);
  }
  __syncthreads();
#pragma unroll
  for (int i = 0; i < 32; i += 8) {
    WTb[(size_t)(p0 + ty + i) * EMBED_DIM + d0 + px] = f2bf(t[px][ty + i]);
  }
}

// ---- single-block bucketing: hist -> scan -> tile table -> scatter ----
__global__ __launch_bounds__(1024) void k_bucket(const int* __restrict__ subs,
                                                 int* __restrict__ tiles,
                                                 int* __restrict__ n_tiles,
                                                 int* __restrict__ perm) {
  __shared__ int h[64], off[64], cur[64];
  const int t = threadIdx.x;
  if (t < 64) h[t] = 0;
  __syncthreads();
  for (int r = t; r < NROWS; r += 1024)
    atomicAdd(&h[subs[2 * r] * NPART + subs[2 * r + 1]], 1);
  __syncthreads();
  if (t < 64) {  // threads 0..63 == wave 0
    int v = h[t], incl = v;
#pragma unroll
    for (int o = 1; o < 64; o <<= 1) { int n = __shfl_up(incl, o); if (t >= o) incl += n; }
    int excl = incl - v;
    off[t] = excl; cur[t] = 0;
    int tc = (v + 127) >> 7, tincl = tc;
#pragma unroll
    for (int o = 1; o < 64; o <<= 1) { int n = __shfl_up(tincl, o); if (t >= o) tincl += n; }
    int texcl = tincl - tc;
    for (int k = 0; k < tc; ++k) {
      tiles[3 * (texcl + k) + 0] = excl + k * 128;
      tiles[3 * (texcl + k) + 1] = min(128, v - k * 128);
      tiles[3 * (texcl + k) + 2] = t;
    }
    if (t == 63) *n_tiles = tincl;
  }
  __syncthreads();
  for (int r = t; r < NROWS; r += 1024) {
    int p = subs[2 * r] * NPART + subs[2 * r + 1];
    perm[off[p] + atomicAdd(&cur[p], 1)] = r;
  }
}

// ---- GEMM1 fused (delta in-register), round-16 structure (best measured):
// 256 thr, 4 waves (1m x 4n), tile BM=64 x BN=256 x BK=32, 2-phase dbuf
// (40KB LDS), XCD-pinned split-K (z = bid&7), T14 ordering. bf16 output.
// Ypart[z][i, 0:256] = bf16( (source-base)[perm[i], z*512..] @ Wsel ) ----
__global__ __launch_bounds__(256) void gemm1(
    const float* __restrict__ base, const float* __restrict__ source,
    const unsigned short* __restrict__ WTb,    // [1024,4096] bf16
    const int* __restrict__ perm,
    const int* __restrict__ tiles, const int* __restrict__ n_tiles,
    unsigned short* __restrict__ Ypart) {      // [KSPLIT][8192][256] bf16
  __shared__ __attribute__((aligned(16))) __bf16 As[2][64 * BK];    // 4KB/buf
  __shared__ __attribute__((aligned(16))) __bf16 Bs[2][256 * BK];   // 16KB/buf

  const int bid  = blockIdx.x;         // [0,2048)
  const int z    = bid & 7;            // XCD-pinned K chunk
  const int th   = bid >> 3;           // [0,256)
  const int tile = th & 127;
  const int half = th >> 7;            // 0/1: which 64-row half of the tile
  if (tile >= *n_tiles) return;
  const int start = tiles[3 * tile + 0];
  const int cnt   = tiles[3 * tile + 1];
  if (half * 64 >= cnt) return;
  const int bkt   = tiles[3 * tile + 2];
  const int s0    = bkt >> 3, s1 = bkt & 7;
  const int kbase = z * KCHUNK;

  const int tid  = threadIdx.x;
  const int lane = tid & 63;
  const int wave = tid >> 6;           // 0..3 == column quarter (wm = 0)

  // A reg-stage slot: 64 rows x 4 k-groups of 8 = 256 slots, 1/thread
  const int at_row = tid >> 2;         // 0..63
  const int at_kg  = (tid & 3) * 8;    // 0/8/16/24
  const int arow_g = perm[start + min(half * 64 + at_row, cnt - 1)];
  const float* abase = base   + (size_t)arow_g * EMBED_DIM + kbase + at_kg;
  const float* asrc  = source + (size_t)arow_g * EMBED_DIM + kbase + at_kg;

  // B stage: 16 chunks of 16 rows (256 selected W-cols); 4 stage16/thread
  const unsigned short* bptr[4];
#pragma unroll
  for (int it = 0; it < 4; ++it) {
    const int r   = (it * 4 + wave) * 16 + (lane >> 2);   // 0..255
    const int sel = (r < 128) ? (s0 * PARTSZ + r) : (s1 * PARTSZ + r - 128);
    bptr[it] = WTb + (size_t)sel * EMBED_DIM + kbase + (lane & 3) * 8;
  }

  float4 ab0, ab1, as0, as1;  // in-flight base/source (T14 split)

#define ALOAD(kt)                                                           \
  {                                                                         \
    ab0 = *(const float4*)(abase + (kt));                                   \
    ab1 = *(const float4*)(abase + (kt) + 4);                               \
    as0 = *(const float4*)(asrc + (kt));                                    \
    as1 = *(const float4*)(asrc + (kt) + 4);                                \
  }

#define ASTORE(buf)                                                         \
  {                                                                         \
    ushort8_t o;                                                            \
    o[0] = f2bf(as0.x - ab0.x); o[1] = f2bf(as0.y - ab0.y);                 \
    o[2] = f2bf(as0.z - ab0.z); o[3] = f2bf(as0.w - ab0.w);                 \
    o[4] = f2bf(as1.x - ab1.x); o[5] = f2bf(as1.y - ab1.y);                 \
    o[6] = f2bf(as1.z - ab1.z); o[7] = f2bf(as1.w - ab1.w);                 \
    *(ushort8_t*)&As[buf][at_row * BK + at_kg] = o;                         \
  }

#define BSTAGE(buf, kt)                                                     \
  {                                                                         \
    _Pragma("unroll") for (int it = 0; it < 4; ++it) {                      \
      const int c = it * 4 + wave;                                          \
      stage16(bptr[it] + (kt), (char*)&Bs[buf][0] + c * 1024);              \
    }                                                                       \
  }

#define COMPUTE1(buf)                                                       \
  {                                                                         \
    bf16x8_t af[4], bv[4];                                                  \
    _Pragma("unroll") for (int i = 0; i < 4; ++i)                           \
      af[i] = *reinterpret_cast<const bf16x8_t*>(                           \
          &As[buf][(i * 16 + (lane & 15)) * BK + (lane >> 4) * 8]);         \
    _Pragma("unroll") for (int j = 0; j < 4; ++j)                           \
      bv[j] = *reinterpret_cast<const bf16x8_t*>(                           \
          &Bs[buf][(wave * 64 + j * 16 + (lane & 15)) * BK + (lane >> 4) * 8]); \
    _Pragma("unroll") for (int i = 0; i < 4; ++i)                           \
      _Pragma("unroll") for (int j = 0; j < 4; ++j)                         \
        acc[i][j] = __builtin_amdgcn_mfma_f32_16x16x32_bf16(bv[j], af[i],   \
                                                            acc[i][j], 0, 0, 0); \
  }

  f32x4_t acc[4][4] = {};

  // prologue: stage chunk 0 (A latency exposed once)
  ALOAD(0);
  BSTAGE(0, 0);
  ASTORE(0);
  __syncthreads();
  int cur = 0;
  for (int kt = 0; kt < KCHUNK; kt += BK) {
    const bool more = (kt + BK < KCHUNK);
    if (more) {
      ALOAD(kt + BK);           // issue HBM loads...
      BSTAGE(cur ^ 1, kt + BK); // ...and L2 B-staging
    }
    COMPUTE1(cur);              // MFMAs hide the A-load latency
    if (more) ASTORE(cur ^ 1);  // vmcnt wait lands here, after compute
    __syncthreads();
    cur ^= 1;
  }

  unsigned short* Yo = Ypart + (size_t)z * NROWS * KSEL;
#pragma unroll
  for (int i = 0; i < 4; ++i) {
    const int row_local = half * 64 + i * 16 + (lane & 15);
    if (row_local < cnt) {
#pragma unroll
      for (int j = 0; j < 4; ++j) {
        const int col = wave * 64 + j * 16 + (lane >> 4) * 4;
        ushort4 o;
        o.x = f2bf(acc[i][j][0]); o.y = f2bf(acc[i][j][1]);
        o.z = f2bf(acc[i][j][2]); o.w = f2bf(acc[i][j][3]);
        *reinterpret_cast<ushort4*>(
            &Yo[(size_t)(start + row_local) * KSEL + col]) = o;
      }
    }
  }
}

// ---- combine bf16 split-K partials (8) -> Ysel bf16 [8192, 256] ----
__global__ __launch_bounds__(256) void combine(const unsigned short* __restrict__ Yp,
                                               unsigned short* __restrict__ Ysel) {
  const int total = NROWS * KSEL / 4;
  const int stride4 = NROWS * KSEL / 4;   // in ushort4 units
  for (int i = blockIdx.x * blockDim.x + threadIdx.x; i < total;
       i += gridDim.x * blockDim.x) {
    float sx = 0.f, sy = 0.f, sz = 0.f, sw = 0.f;
#pragma unroll
    for (int z = 0; z < KSPLIT; ++z) {
      ushort4 v = ((const ushort4*)Yp)[(size_t)z * stride4 + i];
      sx += bf2f(v.x); sy += bf2f(v.y); sz += bf2f(v.z); sw += bf2f(v.w);
    }
    ushort4 o;
    o.x = f2bf(sx); o.y = f2bf(sy); o.z = f2bf(sz); o.w = f2bf(sw);
    ((ushort4*)Ysel)[i] = o;
  }
}

// ---- GEMM2: 512 threads, tile 128 rows x 256 cols, BK=32, 2-phase dbuf,
// XCD-pinned (round-15 proven, byte-identical).
// out[perm[i],:] = base[perm[i],:] + Ysel[i,:] @ Wsel^T ----
__global__ __launch_bounds__(512) void gemm2(
    const unsigned short* __restrict__ Ysel,   // [8192, 256] bf16
    const unsigned short* __restrict__ Wb,     // [4096,1024] bf16
    const int* __restrict__ perm,
    const int* __restrict__ tiles, const int* __restrict__ n_tiles,
    const float* __restrict__ base, float* __restrict__ out) {
  __shared__ __attribute__((aligned(16))) __bf16 As[2][128 * BK];  // 8KB/buf
  __shared__ __attribute__((aligned(16))) __bf16 Bs[2][256 * BK];  // 16KB/buf

  const int bid  = blockIdx.x + blockIdx.y * gridDim.x;
  const int xcd  = bid & 7;
  const int j_   = bid >> 3;           // [0,256)
  const int tile = j_ & 127;
  const int npnl = xcd * 2 + (j_ >> 7);  // [0,16)

  if (tile >= *n_tiles) return;
  const int start = tiles[3 * tile + 0];
  const int cnt   = tiles[3 * tile + 1];
  const int bkt   = tiles[3 * tile + 2];
  const int s0    = bkt >> 3, s1 = bkt & 7;
  const int n0    = npnl * 256;

  const int tid  = threadIdx.x;        // 0..511
  const int lane = tid & 63;
  const int wave = tid >> 6;           // 0..7
  const int wm   = wave >> 2;          // 0..1
  const int wn   = wave & 3;           // 0..3

  const int arow = tid >> 2;           // 0..127
  const int akel = (tid & 3) * 8;
  const int arc  = arow < cnt ? arow : 0;
  const unsigned short* aptr = Ysel + (size_t)(start + arc) * KSEL + akel;

  const unsigned short* bptr[2];
#pragma unroll
  for (int q = 0; q < 2; ++q) {
    const int sidx = q * 512 + tid;
    const int brow = sidx >> 2;        // 0..255
    bptr[q] = Wb + (size_t)(n0 + brow) * PROJ_DIM + (sidx & 3) * 8;
  }

#define STAGE2(buf, kt)                                                        \
  {                                                                            \
    const int sp   = ((kt) < 128) ? s0 : s1;                                   \
    const int coff = sp * PARTSZ + ((kt) & 127);                               \
    stage16(aptr + (kt), (char*)&As[buf][0] + tid * 16);                       \
    stage16(bptr[0] + coff, (char*)&Bs[buf][0] + tid * 16);                    \
    stage16(bptr[1] + coff, (char*)&Bs[buf][0] + 8192 + tid * 16);             \
  }

  f32x4_t acc[4][4] = {};

  STAGE2(0, 0);
  __syncthreads();
  int cur = 0;
#pragma unroll
  for (int kt = 0; kt < KSEL; kt += BK) {
    if (kt + BK < KSEL) STAGE2(cur ^ 1, kt + BK);
    bf16x8_t af[4], bv[4];
#pragma unroll
    for (int i = 0; i < 4; ++i)
      af[i] = *reinterpret_cast<const bf16x8_t*>(
          &As[cur][(wm * 64 + i * 16 + (lane & 15)) * BK + (lane >> 4) * 8]);
#pragma unroll
    for (int j = 0; j < 4; ++j)
      bv[j] = *reinterpret_cast<const bf16x8_t*>(
          &Bs[cur][(wn * 64 + j * 16 + (lane & 15)) * BK + (lane >> 4) * 8]);
    // swapped operands -> lane holds 4 consecutive output cols of one row
#pragma unroll
    for (int i = 0; i < 4; ++i)
#pragma unroll
      for (int j = 0; j < 4; ++j)
        acc[i][j] = __builtin_amdgcn_mfma_f32_16x16x32_bf16(bv[j], af[i],
                                                            acc[i][j], 0, 0, 0);
    __syncthreads();
    cur ^= 1;
  }

#pragma unroll
  for (int i = 0; i < 4; ++i) {
    const int row_local = wm * 64 + i * 16 + (lane & 15);
    if (row_local < cnt) {
      const int grow = perm[start + row_local];
#pragma unroll
      for (int j = 0; j < 4; ++j) {
        const int col = n0 + wn * 64 + j * 16 + (lane >> 4) * 4;
        const size_t o = (size_t)grow * EMBED_DIM + col;
        f32x4_t b4 = *reinterpret_cast<const f32x4_t*>(&base[o]);
        *reinterpret_cast<f32x4_t*>(&out[o]) = acc[i][j] + b4;
      }
    }
  }
}

extern "C" void kernel_launch(void* const* d_in, const int* in_sizes, int n_in,
                              void* d_out, int out_size, void* d_ws, size_t ws_size,
                              hipStream_t stream) {
  const float* base   = (const float*)d_in[0];
  const float* source = (const float*)d_in[1];
  const int*   subs   = (const int*)d_in[2];
  const float* W      = (const float*)d_in[3];
  float* out = (float*)d_out;

  // d_out scratch (dead before gemm2 writes out):
  //   Ypart bf16 [8][8192][256] @ 0   (32 MB; d_out is 128 MB)
  unsigned short* Ypart = (unsigned short*)d_out;

  // ws: Wb 8MB | WTb 8MB | Ysel 4MB | meta
  char* ws = (char*)d_ws;
  unsigned short* Wb   = (unsigned short*)(ws);
  unsigned short* WTb  = (unsigned short*)(ws + (8u << 20));
  unsigned short* Ysel = (unsigned short*)(ws + (16u << 20));
  char* meta = ws + (21u << 20);
  int* n_tiles = (int*)(meta);
  int* tiles   = (int*)(meta + 256);   // 128*3 ints
  int* perm    = (int*)(meta + 4096);  // 8192 ints

  k_bucket<<<1, 1024, 0, stream>>>(subs, tiles, n_tiles, perm);

  prep_w<<<dim3(PROJ_DIM / 32, EMBED_DIM / 32), 256, 0, stream>>>(W, Wb, WTb);

  gemm1<<<MAXTILES * 2 * KSPLIT, 256, 0, stream>>>(base, source, WTb, perm,
                                                   tiles, n_tiles, Ypart);
  combine<<<1024, 256, 0, stream>>>(Ypart, Ysel);

  gemm2<<<dim3(MAXTILES, EMBED_DIM / 256), 512, 0, stream>>>(Ysel, Wb, perm, tiles,
                                                             n_tiles, base, out);
}